// Round 6
// baseline (1598.141 us; speedup 1.0000x reference)
//
#include <hip/hip_runtime.h>
#include <math.h>

#define N_NODES 100000
#define N_EDGES 1600000

static constexpr int GG = (N_NODES + 63) / 64;        // 1563
static constexpr int NODE_GRID = (N_NODES + 255) / 256; // 391
static constexpr int DG4 = (N_NODES / 4 + 63) / 64;   // 391 blocks for dense_conv_t4
static constexpr unsigned M_INIT = 0x007FFFFFu;       // fmap(-inf)

typedef __attribute__((ext_vector_type(8))) short          bf16x8;
typedef __attribute__((ext_vector_type(8))) unsigned short ushort8_t;
typedef __attribute__((ext_vector_type(4))) unsigned short ushort4_t;
typedef __attribute__((ext_vector_type(4))) float          f32x4;

__device__ __forceinline__ float lrelu(float v, float s){ return v >= 0.f ? v : v*s; }

__device__ __forceinline__ unsigned fmap(float v){
    unsigned u = __float_as_uint(v);
    return (u & 0x80000000u) ? ~u : (u | 0x80000000u);
}

__device__ __forceinline__ unsigned short f2bf(float f){
    unsigned u = __float_as_uint(f);
    unsigned r = (u + 0x7FFFu + ((u >> 16) & 1u)) >> 16;   // RNE
    return (unsigned short)r;
}
__device__ __forceinline__ float bf2f(unsigned short h){
    return __uint_as_float(((unsigned)h) << 16);
}

// ---------------- weight split: wt_hi/lo[n][k] = hi/lo bf16 of w[k][n] ----------------
__global__ void cvt_wT_split(const float* __restrict__ w,
                             unsigned short* __restrict__ whi,
                             unsigned short* __restrict__ wlo,
                             int K, int Nsrc, int Npad)
{
    int idx = blockIdx.x * 256 + threadIdx.x;
    if (idx >= Npad * K) return;
    int n = idx / K, k = idx % K;
    float v = (n < Nsrc) ? w[(long)k * Nsrc + n] : 0.f;
    unsigned short hi = f2bf(v);
    whi[idx] = hi;
    wlo[idx] = f2bf(v - bf2f(hi));
}

// ---------------- hi/lo MFMA MLP layer: Out[f32 N x 256] = leaky(A @ W^T + bias) ------
// A f32 [N][KV] (may alias Out: block reads only its own 64 rows before writing them).
// W pre-split bf16 hi/lo [256][KV]. 3 MFMAs per product pair -> ~f32 precision.
template<int KV>
__global__ __launch_bounds__(256) void mlp_mfma_hilo(
    const float* __restrict__ A,
    const unsigned short* __restrict__ wth, const unsigned short* __restrict__ wtl,
    const float* __restrict__ bias, float* __restrict__ Out)
{
    constexpr int AS = KV + 8;
    __shared__ unsigned short lds_hi[64 * AS];
    __shared__ unsigned short lds_lo[64 * AS];
    const int t = threadIdx.x;
    const int r0 = blockIdx.x * 64;
    const int wv = t >> 6, lane = t & 63;
    const int l15 = lane & 15, grp = lane >> 4;
    const int cw = wv * 64;

    constexpr int cpr = KV / 8;
    for (int c = t; c < 64 * cpr; c += 256) {
        int row = c / cpr, kc = c % cpr;
        int gr = r0 + row;
        float4 v0 = make_float4(0,0,0,0), v1 = v0;
        if (gr < N_NODES) {
            v0 = *(const float4*)(A + (long)gr * KV + kc * 8);
            v1 = *(const float4*)(A + (long)gr * KV + kc * 8 + 4);
        }
        float vs[8] = {v0.x,v0.y,v0.z,v0.w,v1.x,v1.y,v1.z,v1.w};
        unsigned short* ph = lds_hi + row * AS + kc * 8;
        unsigned short* pl = lds_lo + row * AS + kc * 8;
#pragma unroll
        for (int j = 0; j < 8; j++) {
            unsigned short hi = f2bf(vs[j]);
            ph[j] = hi;
            pl[j] = f2bf(vs[j] - bf2f(hi));
        }
    }
    __syncthreads();

    f32x4 acc[4][4];
#pragma unroll
    for (int i = 0; i < 4; i++)
#pragma unroll
        for (int j = 0; j < 4; j++) acc[i][j] = (f32x4){0.f,0.f,0.f,0.f};

#pragma unroll
    for (int ks = 0; ks < KV / 32; ks++) {
        bf16x8 ah[4], al[4], bh[4], bl[4];
#pragma unroll
        for (int i = 0; i < 4; i++) {
            ah[i] = *(const bf16x8*)(lds_hi + (i*16 + l15) * AS + ks*32 + grp*8);
            al[i] = *(const bf16x8*)(lds_lo + (i*16 + l15) * AS + ks*32 + grp*8);
        }
#pragma unroll
        for (int j = 0; j < 4; j++) {
            bh[j] = *(const bf16x8*)(wth + (size_t)(cw + j*16 + l15) * KV + ks*32 + grp*8);
            bl[j] = *(const bf16x8*)(wtl + (size_t)(cw + j*16 + l15) * KV + ks*32 + grp*8);
        }
#pragma unroll
        for (int i = 0; i < 4; i++)
#pragma unroll
            for (int j = 0; j < 4; j++) {
                acc[i][j] = __builtin_amdgcn_mfma_f32_16x16x32_bf16(ah[i], bl[j], acc[i][j], 0, 0, 0);
                acc[i][j] = __builtin_amdgcn_mfma_f32_16x16x32_bf16(al[i], bh[j], acc[i][j], 0, 0, 0);
                acc[i][j] = __builtin_amdgcn_mfma_f32_16x16x32_bf16(ah[i], bh[j], acc[i][j], 0, 0, 0);
            }
    }

    __syncthreads();   // all LDS A-reads done; safe for in-place global write ordering
#pragma unroll
    for (int i = 0; i < 4; i++)
#pragma unroll
        for (int j = 0; j < 4; j++)
#pragma unroll
            for (int r = 0; r < 4; r++) {
                int row = r0 + i*16 + grp*4 + r;
                int col = cw + j*16 + l15;
                if (row < N_NODES) {
                    float v = acc[i][j][r] + bias[col];
                    Out[(long)row * 256 + col] = lrelu(v, 0.01f);
                }
            }
}

// ---------------- hi/lo MFMA MLP layer 3: Xt[24][N] = leaky(A @ W3^T + bias) ---------
__global__ __launch_bounds__(256) void mlp_mfma24_hilo(
    const float* __restrict__ A,
    const unsigned short* __restrict__ wth, const unsigned short* __restrict__ wtl,
    const float* __restrict__ bias, float* __restrict__ XtOut)
{
    constexpr int KV = 256, AS = 264;
    __shared__ unsigned short lds_hi[64 * AS];
    __shared__ unsigned short lds_lo[64 * AS];
    const int t = threadIdx.x;
    const int r0 = blockIdx.x * 64;
    const int wv = t >> 6, lane = t & 63;
    const int l15 = lane & 15, grp = lane >> 4;

    constexpr int cpr = KV / 8;
    for (int c = t; c < 64 * cpr; c += 256) {
        int row = c / cpr, kc = c % cpr;
        int gr = r0 + row;
        float4 v0 = make_float4(0,0,0,0), v1 = v0;
        if (gr < N_NODES) {
            v0 = *(const float4*)(A + (long)gr * KV + kc * 8);
            v1 = *(const float4*)(A + (long)gr * KV + kc * 8 + 4);
        }
        float vs[8] = {v0.x,v0.y,v0.z,v0.w,v1.x,v1.y,v1.z,v1.w};
        unsigned short* ph = lds_hi + row * AS + kc * 8;
        unsigned short* pl = lds_lo + row * AS + kc * 8;
#pragma unroll
        for (int j = 0; j < 8; j++) {
            unsigned short hi = f2bf(vs[j]);
            ph[j] = hi;
            pl[j] = f2bf(vs[j] - bf2f(hi));
        }
    }
    __syncthreads();

    f32x4 acc[2] = {(f32x4){0.f,0.f,0.f,0.f}, (f32x4){0.f,0.f,0.f,0.f}};
#pragma unroll
    for (int ks = 0; ks < KV / 32; ks++) {
        bf16x8 ah = *(const bf16x8*)(lds_hi + (wv*16 + l15) * AS + ks*32 + grp*8);
        bf16x8 al = *(const bf16x8*)(lds_lo + (wv*16 + l15) * AS + ks*32 + grp*8);
#pragma unroll
        for (int j = 0; j < 2; j++) {
            bf16x8 bh = *(const bf16x8*)(wth + (size_t)(j*16 + l15) * KV + ks*32 + grp*8);
            bf16x8 bl = *(const bf16x8*)(wtl + (size_t)(j*16 + l15) * KV + ks*32 + grp*8);
            acc[j] = __builtin_amdgcn_mfma_f32_16x16x32_bf16(ah, bl, acc[j], 0, 0, 0);
            acc[j] = __builtin_amdgcn_mfma_f32_16x16x32_bf16(al, bh, acc[j], 0, 0, 0);
            acc[j] = __builtin_amdgcn_mfma_f32_16x16x32_bf16(ah, bh, acc[j], 0, 0, 0);
        }
    }

    __syncthreads();
    float* ldsf = (float*)lds_hi;               // [64][25] f32 out-stage
#pragma unroll
    for (int j = 0; j < 2; j++)
#pragma unroll
        for (int r = 0; r < 4; r++) {
            int cl = j*16 + l15;
            if (cl < 24) {
                int rl = wv*16 + grp*4 + r;
                float v = acc[j][r] + bias[cl];
                ldsf[rl * 25 + cl] = lrelu(v, 0.01f);
            }
        }
    __syncthreads();
    int n = t & 63, c0 = t >> 6;
    int gr = r0 + n;
    if (gr < N_NODES)
        for (int c = c0; c < 24; c += 4)
            XtOut[(long)c * N_NODES + gr] = ldsf[n * 25 + c];
}

// ---------------- BN stats over channel-major layout ----------------
__global__ void bn_stats_t(const float* __restrict__ Xt,
                           float* __restrict__ gsum, float* __restrict__ gsq)
{
    int ch = blockIdx.x, part = blockIdx.y, t = threadIdx.x;
    const float* p = Xt + (long)ch * N_NODES;
    float s = 0.f, q = 0.f;
    for (long i = (long)part * 25000 + t * 4; i < (long)(part + 1) * 25000; i += 1024) {
        float4 v = *(const float4*)(p + i);
        s += v.x + v.y + v.z + v.w;
        q += v.x*v.x + v.y*v.y + v.z*v.z + v.w*v.w;
    }
#pragma unroll
    for (int m = 1; m < 64; m <<= 1) {
        s += __shfl_xor(s, m, 64);
        q += __shfl_xor(q, m, 64);
    }
    __shared__ float ls[4], lq[4];
    int wid = t >> 6;
    if ((t & 63) == 0) { ls[wid] = s; lq[wid] = q; }
    __syncthreads();
    if (t == 0) {
        atomicAdd(gsum + ch, ls[0] + ls[1] + ls[2] + ls[3]);
        atomicAdd(gsq  + ch, lq[0] + lq[1] + lq[2] + lq[3]);
    }
}

// ---------------- reduce per-block partial stats ----------------
__global__ __launch_bounds__(256) void bn_reduce(
    const float* __restrict__ ps, const float* __restrict__ pq,
    float* __restrict__ gsum, float* __restrict__ gsq, int C)
{
    int g = blockIdx.x;
    int t = threadIdx.x;
    float s = 0.f, q = 0.f;
    for (int b = t; b < DG4; b += 256) {
        s += ps[g * DG4 + b];
        q += pq[g * DG4 + b];
    }
    __shared__ float ls[256], lq[256];
    ls[t] = s; lq[t] = q; __syncthreads();
    for (int o = 128; o > 0; o >>= 1) {
        if (t < o) { ls[t] += ls[t + o]; lq[t] += lq[t + o]; }
        __syncthreads();
    }
    if (t == 0) { gsum[C + g] = ls[0]; gsq[C + g] = lq[0]; }
}

// ---------------- densenet layer, 4 nodes/thread, float4 IO ----------------
__global__ __launch_bounds__(64) void dense_conv_t4(
    float* __restrict__ Xt, int C,
    const float* __restrict__ W, int WS,
    const float* __restrict__ gamma, const float* __restrict__ beta,
    const float* __restrict__ gsum, const float* __restrict__ gsq,
    float* __restrict__ ps, float* __restrict__ pq)
{
    __shared__ float w_lds[12 * 132];
    __shared__ float a_lds[132], b_lds[132];
    int t = threadIdx.x;
    for (int c = t; c < C; c += 64) {
        float mu  = gsum[c] * (1.f / N_NODES);
        float var = gsq[c]  * (1.f / N_NODES) - mu * mu;
        float A = rsqrtf(var + 1e-5f) * gamma[c];
        a_lds[c] = A;
        b_lds[c] = beta[c] - mu * A;
    }
#pragma unroll
    for (int g = 0; g < 12; g++)
        for (int c = t; c < C; c += 64)
            w_lds[g * 132 + c] = W[g * WS + c];
    __syncthreads();

    int tid = blockIdx.x * 64 + t;
    bool valid = (tid < N_NODES / 4);
    long n4 = (long)(valid ? tid : 0) * 4;
    const float* xp = Xt + n4;

    float4 acc[12];
#pragma unroll
    for (int g = 0; g < 12; g++) acc[g] = make_float4(0.f,0.f,0.f,0.f);

    float4 v[12], vn[12];
#pragma unroll
    for (int j = 0; j < 12; j++) v[j] = *(const float4*)(xp + (long)j * N_NODES);
    for (int c0 = 0; c0 < C; c0 += 12) {
        if (c0 + 12 < C) {
#pragma unroll
            for (int j = 0; j < 12; j++)
                vn[j] = *(const float4*)(xp + (long)(c0 + 12 + j) * N_NODES);
        }
#pragma unroll
        for (int j = 0; j < 12; j++) {
            int ch = c0 + j;
            float Ac = a_lds[ch], Bc = b_lds[ch];
            float ux = lrelu(Ac * v[j].x + Bc, 0.01f);
            float uy = lrelu(Ac * v[j].y + Bc, 0.01f);
            float uz = lrelu(Ac * v[j].z + Bc, 0.01f);
            float uw = lrelu(Ac * v[j].w + Bc, 0.01f);
#pragma unroll
            for (int g = 0; g < 12; g++) {
                float wv = w_lds[g * 132 + ch];
                acc[g].x += ux * wv; acc[g].y += uy * wv;
                acc[g].z += uz * wv; acc[g].w += uw * wv;
            }
        }
#pragma unroll
        for (int j = 0; j < 12; j++) v[j] = vn[j];
    }
    if (valid) {
#pragma unroll
        for (int g = 0; g < 12; g++)
            *(float4*)(Xt + (long)(C + g) * N_NODES + n4) = acc[g];
    }
    // per-block partial stats (plain stores; reduced by bn_reduce)
    float sv[12], qv[12];
#pragma unroll
    for (int g = 0; g < 12; g++) {
        float4 a = valid ? acc[g] : make_float4(0.f,0.f,0.f,0.f);
        sv[g] = a.x + a.y + a.z + a.w;
        qv[g] = a.x*a.x + a.y*a.y + a.z*a.z + a.w*a.w;
    }
#pragma unroll
    for (int m = 1; m < 64; m <<= 1)
#pragma unroll
        for (int g = 0; g < 12; g++) {
            sv[g] += __shfl_xor(sv[g], m, 64);
            qv[g] += __shfl_xor(qv[g], m, 64);
        }
    if (t == 0) {
#pragma unroll
        for (int g = 0; g < 12; g++) {
            ps[g * DG4 + blockIdx.x] = sv[g];
            pq[g * DG4 + blockIdx.x] = qv[g];
        }
    }
}

// ---------------- GAT GEMM (f32-exact) + fused scores + bf16 H output -----------
// A channel-major [K][N]; B = gat W [K][F]; avec [2F]. Writes Hb bf16 [N][F], sd, ss.
template<int F>
__global__ __launch_bounds__(256) void gat_gemm(
    const float* __restrict__ A, const float* __restrict__ B,
    const float* __restrict__ avec, int K,
    unsigned short* __restrict__ Hb, float* __restrict__ sd, float* __restrict__ ss)
{
    __shared__ float At[16 * 68];
    __shared__ float Bt[16 * 64];
    __shared__ float ad[64], as_[64];
    const int t  = threadIdx.x;
    const int r0 = blockIdx.x * 64;
    const int tx = t & 15, ty = t >> 4;
    if (t < 64) {
        ad[t]  = (t < F) ? avec[t]     : 0.f;
        as_[t] = (t < F) ? avec[F + t] : 0.f;
    }

    float acc[4][4];
#pragma unroll
    for (int i = 0; i < 4; i++)
#pragma unroll
        for (int j = 0; j < 4; j++) acc[i][j] = 0.f;

    for (int k0 = 0; k0 < K; k0 += 16) {
        {   // stage A (channel-major, coalesced)
            int kk = t >> 4, rq = t & 15;
            float4 v = make_float4(0.f,0.f,0.f,0.f);
            if (k0 + kk < K)
                v = *(const float4*)(A + (long)(k0 + kk) * N_NODES + r0 + rq * 4);
            *(float4*)(At + kk * 68 + rq * 4) = v;
        }
        for (int i = t; i < 16 * 64; i += 256) {   // stage B [16][64], scalar (F=48/60)
            int kk = i >> 6, mq = i & 63;
            float v = 0.f;
            if (k0 + kk < K && mq < F) v = B[(long)(k0 + kk) * F + mq];
            Bt[kk * 64 + mq] = v;
        }
        __syncthreads();
#pragma unroll
        for (int kk = 0; kk < 16; kk++) {
            float4 av = *(const float4*)(At + kk * 68 + ty * 4);
            float4 bv = *(const float4*)(Bt + kk * 64 + tx * 4);
            float a_[4] = {av.x, av.y, av.z, av.w};
            float b_[4] = {bv.x, bv.y, bv.z, bv.w};
#pragma unroll
            for (int i = 0; i < 4; i++)
#pragma unroll
                for (int j = 0; j < 4; j++)
                    acc[i][j] += a_[i] * b_[j];
        }
        __syncthreads();
    }

#pragma unroll
    for (int i = 0; i < 4; i++) {
        int row = r0 + ty * 4 + i;
        // fused scores: exact f32 dot with attention vector halves
        float pd = 0.f, pq_ = 0.f;
#pragma unroll
        for (int j = 0; j < 4; j++) {
            int col = tx * 4 + j;
            pd  += acc[i][j] * ad[col];
            pq_ += acc[i][j] * as_[col];
        }
#pragma unroll
        for (int m = 1; m < 16; m <<= 1) {
            pd  += __shfl_xor(pd,  m, 64);
            pq_ += __shfl_xor(pq_, m, 64);
        }
        if (row < N_NODES) {
            if (tx == 0) { sd[row] = pd; ss[row] = pq_; }
            if (tx * 4 < F) {
                ushort4_t u;
#pragma unroll
                for (int j = 0; j < 4; j++) u[j] = f2bf(acc[i][j]);
                *(ushort4_t*)(Hb + (long)row * F + tx * 4) = u;
            }
        }
    }
}

// ---------------- GAT edge kernels ----------------
__global__ void gat_init(unsigned* __restrict__ m_u, float* __restrict__ den)
{
    long n = (long)blockIdx.x * 256 + threadIdx.x;
    if (n >= N_NODES) return;
    m_u[n] = M_INIT;
    den[n] = 0.f;
}

__global__ void gat_edge1(const int* __restrict__ src, const int* __restrict__ dst,
                          const float* __restrict__ sd, const float* __restrict__ ss,
                          unsigned* __restrict__ m_u)
{
    for (long e = (long)blockIdx.x * 256 + threadIdx.x; e < N_EDGES; e += (long)gridDim.x * 256) {
        int d = dst[e], s = src[e];
        float v = sd[d] + ss[s];
        v = (v >= 0.f) ? v : 0.2f * v;
        atomicMax(m_u + d, fmap(v));
    }
}

__global__ void gat_fixm(unsigned* __restrict__ m_u)
{
    long n = (long)blockIdx.x * 256 + threadIdx.x;
    if (n >= N_NODES) return;
    unsigned u = m_u[n];
    float m;
    if (u == M_INIT) m = 0.f;
    else m = (u & 0x80000000u) ? __uint_as_float(u ^ 0x80000000u) : __uint_as_float(~u);
    m_u[n] = __float_as_uint(m);
}

__global__ void gat_edge2(const int* __restrict__ src, const int* __restrict__ dst,
                          const float* __restrict__ sd, const float* __restrict__ ss,
                          const float* __restrict__ mf, float* __restrict__ exv,
                          float* __restrict__ den)
{
    for (long e = (long)blockIdx.x * 256 + threadIdx.x; e < N_EDGES; e += (long)gridDim.x * 256) {
        int d = dst[e], s = src[e];
        float v = sd[d] + ss[s];
        v = (v >= 0.f) ? v : 0.2f * v;
        float x = __expf(v - mf[d]);
        exv[e] = x;
        atomicAdd(den + d, x);
    }
}

// wave per node; bf16 H gather (halved bytes); outT[ch][n] f32
__global__ __launch_bounds__(256) void gat_aggregate(
    const int* __restrict__ src, const float* __restrict__ exv,
    const float* __restrict__ den, const int* __restrict__ rstart,
    const int* __restrict__ csr, const unsigned short* __restrict__ Hb, int F,
    const float* __restrict__ bias, float* __restrict__ outT)
{
    int wid  = threadIdx.x >> 6;
    int lane = threadIdx.x & 63;
    long node = (long)blockIdx.x * 4 + wid;
    if (node >= N_NODES) return;
    int st = rstart[node], en = rstart[node + 1];
    float invden = 1.f / (den[node] + 1e-16f);
    float acc = 0.f;
    for (int base = st; base < en; base += 64) {
        int cnt = min(64, en - base);
        float al = 0.f; int sj = 0;
        if (lane < cnt) {
            int eid = csr[base + lane];
            al = exv[eid] * invden;
            sj = src[eid];
        }
        for (int j = 0; j < cnt; j++) {
            float a = __shfl(al, j, 64);
            int   s = __shfl(sj, j, 64);
            if (lane < F) acc += a * bf2f(Hb[(long)s * F + lane]);
        }
    }
    if (lane < F) outT[(long)lane * N_NODES + node] = acc + bias[lane];
}

// ---------------- final transpose [132][N] -> [N,132] ----------------
__global__ __launch_bounds__(256) void transpose_out(const float* __restrict__ Xt,
                                                     float* __restrict__ out)
{
    __shared__ float tile[64 * 133];
    int t = threadIdx.x;
    long n0 = (long)blockIdx.x * 64;
    int lane = t & 63, cq = t >> 6;
    for (int c = cq; c < 132; c += 4) {
        long n = n0 + lane;
        float v = (n < N_NODES) ? Xt[(long)c * N_NODES + n] : 0.f;
        tile[lane * 133 + c] = v;
    }
    __syncthreads();
    for (int idx = t; idx < 64 * 132; idx += 256) {
        int r = idx / 132, c = idx % 132;
        long n = n0 + r;
        if (n < N_NODES) out[n * 132 + c] = tile[r * 133 + c];
    }
}

// ---------------- CSR build ----------------
__global__ void hist_kernel(const int* __restrict__ dst, int* __restrict__ deg)
{
    for (long e = (long)blockIdx.x * 256 + threadIdx.x; e < N_EDGES; e += (long)gridDim.x * 256)
        atomicAdd(deg + dst[e], 1);
}

__global__ void scan1(const int* __restrict__ deg, int* __restrict__ rtmp, int* __restrict__ parts)
{
    __shared__ int ls[256];
    int t = threadIdx.x;
    long i = (long)blockIdx.x * 256 + t;
    int v = (i < N_NODES) ? deg[i] : 0;
    ls[t] = v; __syncthreads();
    for (int o = 1; o < 256; o <<= 1) {
        int y = (t >= o) ? ls[t - o] : 0;
        __syncthreads();
        ls[t] += y;
        __syncthreads();
    }
    if (i < N_NODES) rtmp[i] = ls[t] - v;
    if (t == 255) parts[blockIdx.x] = ls[255];
}

__global__ void scan2(int* __restrict__ parts, int nb, int* __restrict__ total_out)
{
    __shared__ int ls[512];
    int t = threadIdx.x;
    int v = (t < nb) ? parts[t] : 0;
    ls[t] = v; __syncthreads();
    for (int o = 1; o < 512; o <<= 1) {
        int y = (t >= o) ? ls[t - o] : 0;
        __syncthreads();
        ls[t] += y;
        __syncthreads();
    }
    if (t < nb) parts[t] = ls[t] - v;
    if (t == 0) total_out[0] = ls[511];
}

__global__ void scan3(const int* __restrict__ rtmp, const int* __restrict__ parts,
                      int* __restrict__ rstart, int* __restrict__ cursor)
{
    long i = (long)blockIdx.x * 256 + threadIdx.x;
    if (i < N_NODES) {
        int v = rtmp[i] + parts[i >> 8];
        rstart[i] = v;
        cursor[i] = v;
    }
}

__global__ void scatter_k(const int* __restrict__ dst, int* __restrict__ cursor,
                          int* __restrict__ csr)
{
    for (long e = (long)blockIdx.x * 256 + threadIdx.x; e < N_EDGES; e += (long)gridDim.x * 256) {
        int pos = atomicAdd(cursor + dst[e], 1);
        csr[pos] = (int)e;
    }
}

// ---------------- host helpers ----------------
static void run_dense_block_t(hipStream_t stream, float* Xt, int C0,
                              const float* convW, int WS,
                              const float* gamma, const float* beta,
                              float* gsum, float* gsq, float* ps, float* pq)
{
    hipMemsetAsync(gsum, 0, 264 * sizeof(float), stream);
    bn_stats_t<<<dim3(C0, 4), 256, 0, stream>>>(Xt, gsum, gsq);
    for (int i = 0; i < 6; i++) {
        int C = C0 + 12 * i;
        dense_conv_t4<<<DG4, 64, 0, stream>>>(Xt, C, convW + (size_t)i * 12 * WS, WS,
                                              gamma + (size_t)i * WS, beta + (size_t)i * WS,
                                              gsum, gsq, ps, pq);
        if (i < 5)
            bn_reduce<<<12, 256, 0, stream>>>(ps, pq, gsum, gsq, C);
    }
}

template<int F>
static void run_gat(hipStream_t stream, const float* XtIn, int K,
                    const float* W, const float* avec, const float* bias,
                    unsigned short* Hb, float* outT,
                    const int* src, const int* dst,
                    float* sd, float* ss, unsigned* m_u, float* den,
                    float* exv, const int* rstart, const int* csr)
{
    gat_gemm<F><<<GG, 256, 0, stream>>>(XtIn, W, avec, K, Hb, sd, ss);
    gat_init<<<NODE_GRID, 256, 0, stream>>>(m_u, den);
    gat_edge1<<<2048, 256, 0, stream>>>(src, dst, sd, ss, m_u);
    gat_fixm<<<NODE_GRID, 256, 0, stream>>>(m_u);
    gat_edge2<<<2048, 256, 0, stream>>>(src, dst, sd, ss, (const float*)m_u, exv, den);
    gat_aggregate<<<(N_NODES + 3) / 4, 256, 0, stream>>>(src, exv, den, rstart, csr,
                                                         Hb, F, bias, outT);
}

extern "C" void kernel_launch(void* const* d_in, const int* in_sizes, int n_in,
                              void* d_out, int out_size, void* d_ws, size_t ws_size,
                              hipStream_t stream)
{
    const float* x     = (const float*)d_in[0];
    const int*   src   = (const int*)d_in[1];
    const int*   dst   = (const int*)d_in[2];
    const float* w1    = (const float*)d_in[3];
    const float* b1    = (const float*)d_in[4];
    const float* w2    = (const float*)d_in[5];
    const float* b2    = (const float*)d_in[6];
    const float* w3    = (const float*)d_in[7];
    const float* b3    = (const float*)d_in[8];
    const float* conv1 = (const float*)d_in[9];
    const float* bn1g  = (const float*)d_in[10];
    const float* bn1b  = (const float*)d_in[11];
    const float* g1w   = (const float*)d_in[12];
    const float* g1a   = (const float*)d_in[13];
    const float* g1b   = (const float*)d_in[14];
    const float* conv2 = (const float*)d_in[15];
    const float* bn2g  = (const float*)d_in[16];
    const float* bn2b  = (const float*)d_in[17];
    const float* g2w   = (const float*)d_in[18];
    const float* g2a   = (const float*)d_in[19];
    const float* g2b   = (const float*)d_in[20];
    const float* conv3 = (const float*)d_in[21];
    const float* bn3g  = (const float*)d_in[22];
    const float* bn3b  = (const float*)d_in[23];
    float* out = (float*)d_out;

    char* ws = (char*)d_ws;
    size_t off = 0;
    auto alloc = [&](size_t bytes) -> void* {
        void* p = ws + off;
        off += (bytes + 255) & ~(size_t)255;
        return p;
    };
    float*    h      = (float*)alloc((size_t)N_NODES * 256 * 4); // MLP f32; later Hb + Xt3
    float*    Xt1    = (float*)alloc((size_t)96  * N_NODES * 4);
    float*    Xt2    = (float*)alloc((size_t)120 * N_NODES * 4);
    float*    exv    = (float*)alloc((size_t)N_EDGES * 4);
    int*      csr    = (int*)alloc((size_t)N_EDGES * 4);
    int*      deg    = (int*)alloc((size_t)N_NODES * 4);
    int*      rtmp   = (int*)alloc((size_t)N_NODES * 4);
    int*      rstart = (int*)alloc((size_t)(N_NODES + 1) * 4);
    int*      cursor = (int*)alloc((size_t)N_NODES * 4);
    int*      parts  = (int*)alloc(2048);
    unsigned* m_u    = (unsigned*)alloc((size_t)N_NODES * 4);
    float*    den    = (float*)alloc((size_t)N_NODES * 4);
    float*    sd     = (float*)alloc((size_t)N_NODES * 4);
    float*    ss     = (float*)alloc((size_t)N_NODES * 4);
    float*    gsum   = (float*)alloc(264 * 4);
    float*    gsq    = gsum + 132;
    float*    ps     = (float*)alloc((size_t)12 * DG4 * 4);
    float*    pq     = (float*)alloc((size_t)12 * DG4 * 4);
    unsigned short* wt1h = (unsigned short*)alloc(256 * 64  * 2);
    unsigned short* wt1l = (unsigned short*)alloc(256 * 64  * 2);
    unsigned short* wt2h = (unsigned short*)alloc(256 * 256 * 2);
    unsigned short* wt2l = (unsigned short*)alloc(256 * 256 * 2);
    unsigned short* wt3h = (unsigned short*)alloc(32  * 256 * 2);
    unsigned short* wt3l = (unsigned short*)alloc(32  * 256 * 2);

    // overlays in h (102.4 MB), dead after the MLP:
    unsigned short* H1b = (unsigned short*)h;            // [N][48] bf16 = 9.6 MB
    unsigned short* H2b = (unsigned short*)h;            // [N][60] bf16 = 12 MB
    float* Xt3 = (float*)((char*)h + (size_t)16 * 1024 * 1024); // [132][N] f32 = 52.8 MB

    // ---- CSR by dst (shared by both GATs) ----
    hipMemsetAsync(deg, 0, (size_t)N_NODES * 4, stream);
    hist_kernel<<<2048, 256, 0, stream>>>(dst, deg);
    scan1<<<NODE_GRID, 256, 0, stream>>>(deg, rtmp, parts);
    scan2<<<1, 512, 0, stream>>>(parts, NODE_GRID, rstart + N_NODES);
    scan3<<<NODE_GRID, 256, 0, stream>>>(rtmp, parts, rstart, cursor);
    scatter_k<<<2048, 256, 0, stream>>>(dst, cursor, csr);

    // ---- weight prep (f32 -> transposed hi/lo bf16) ----
    cvt_wT_split<<<(256 * 64  + 255) / 256, 256, 0, stream>>>(w1, wt1h, wt1l, 64,  256, 256);
    cvt_wT_split<<<(256 * 256 + 255) / 256, 256, 0, stream>>>(w2, wt2h, wt2l, 256, 256, 256);
    cvt_wT_split<<<(32  * 256 + 255) / 256, 256, 0, stream>>>(w3, wt3h, wt3l, 256, 24,  32);

    // ---- MLP (hi/lo bf16 MFMA, ~f32 precision, f32 intermediates) ----
    mlp_mfma_hilo<64> <<<GG, 256, 0, stream>>>(x, wt1h, wt1l, b1, h);
    mlp_mfma_hilo<256><<<GG, 256, 0, stream>>>(h, wt2h, wt2l, b2, h);   // in-place
    mlp_mfma24_hilo<<<GG, 256, 0, stream>>>(h, wt3h, wt3l, b3, Xt1);

    // ---- dense block 1 (24 -> 96, channel-major) ----
    run_dense_block_t(stream, Xt1, 24, conv1, 84, bn1g, bn1b, gsum, gsq, ps, pq);

    // ---- GAT 1 (96 -> 48), output transposed into Xt2 rows 0..47 ----
    run_gat<48>(stream, Xt1, 96, g1w, g1a, g1b, H1b, Xt2,
                src, dst, sd, ss, m_u, den, exv, rstart, csr);

    // ---- dense block 2 (48 -> 120) ----
    run_dense_block_t(stream, Xt2, 48, conv2, 108, bn2g, bn2b, gsum, gsq, ps, pq);

    // ---- GAT 2 (120 -> 60), output transposed into Xt3 rows 0..59 ----
    run_gat<60>(stream, Xt2, 120, g2w, g2a, g2b, H2b, Xt3,
                src, dst, sd, ss, m_u, den, exv, rstart, csr);

    // ---- dense block 3 (60 -> 132) ----
    run_dense_block_t(stream, Xt3, 60, conv3, 120, bn3g, bn3b, gsum, gsq, ps, pq);

    // ---- final transpose to row-major d_out ----
    transpose_out<<<GG, 256, 0, stream>>>(Xt3, out);
}

// Round 7
// 1251.276 us; speedup vs baseline: 1.2772x; 1.2772x over previous
//
#include <hip/hip_runtime.h>
#include <math.h>

#define N_NODES 100000
#define N_EDGES 1600000

static constexpr int GG = (N_NODES + 63) / 64;        // 1563
static constexpr int NODE_GRID = (N_NODES + 255) / 256; // 391
static constexpr int DG4 = (N_NODES / 4 + 63) / 64;   // 391 blocks for dense_conv_t4

typedef __attribute__((ext_vector_type(8))) short          bf16x8;
typedef __attribute__((ext_vector_type(8))) unsigned short ushort8_t;
typedef __attribute__((ext_vector_type(4))) unsigned short ushort4_t;
typedef __attribute__((ext_vector_type(4))) float          f32x4;

__device__ __forceinline__ float lrelu(float v, float s){ return v >= 0.f ? v : v*s; }

__device__ __forceinline__ unsigned short f2bf(float f){
    unsigned u = __float_as_uint(f);
    unsigned r = (u + 0x7FFFu + ((u >> 16) & 1u)) >> 16;   // RNE
    return (unsigned short)r;
}
__device__ __forceinline__ float bf2f(unsigned short h){
    return __uint_as_float(((unsigned)h) << 16);
}

// ---------------- weight split: wt_hi/lo[n][k] = hi/lo bf16 of w[k][n] ----------------
__global__ void cvt_wT_split(const float* __restrict__ w,
                             unsigned short* __restrict__ whi,
                             unsigned short* __restrict__ wlo,
                             int K, int Nsrc, int Npad)
{
    int idx = blockIdx.x * 256 + threadIdx.x;
    if (idx >= Npad * K) return;
    int n = idx / K, k = idx % K;
    float v = (n < Nsrc) ? w[(long)k * Nsrc + n] : 0.f;
    unsigned short hi = f2bf(v);
    whi[idx] = hi;
    wlo[idx] = f2bf(v - bf2f(hi));
}

// ---------------- hi/lo MFMA MLP layer: Out[f32 N x 256] = leaky(A @ W^T + bias) ------
template<int KV>
__global__ __launch_bounds__(256) void mlp_mfma_hilo(
    const float* __restrict__ A,
    const unsigned short* __restrict__ wth, const unsigned short* __restrict__ wtl,
    const float* __restrict__ bias, float* __restrict__ Out)
{
    constexpr int AS = KV + 8;
    __shared__ unsigned short lds_hi[64 * AS];
    __shared__ unsigned short lds_lo[64 * AS];
    const int t = threadIdx.x;
    const int r0 = blockIdx.x * 64;
    const int wv = t >> 6, lane = t & 63;
    const int l15 = lane & 15, grp = lane >> 4;
    const int cw = wv * 64;

    constexpr int cpr = KV / 8;
    for (int c = t; c < 64 * cpr; c += 256) {
        int row = c / cpr, kc = c % cpr;
        int gr = r0 + row;
        float4 v0 = make_float4(0,0,0,0), v1 = v0;
        if (gr < N_NODES) {
            v0 = *(const float4*)(A + (long)gr * KV + kc * 8);
            v1 = *(const float4*)(A + (long)gr * KV + kc * 8 + 4);
        }
        float vs[8] = {v0.x,v0.y,v0.z,v0.w,v1.x,v1.y,v1.z,v1.w};
        unsigned short* ph = lds_hi + row * AS + kc * 8;
        unsigned short* pl = lds_lo + row * AS + kc * 8;
#pragma unroll
        for (int j = 0; j < 8; j++) {
            unsigned short hi = f2bf(vs[j]);
            ph[j] = hi;
            pl[j] = f2bf(vs[j] - bf2f(hi));
        }
    }
    __syncthreads();

    f32x4 acc[4][4];
#pragma unroll
    for (int i = 0; i < 4; i++)
#pragma unroll
        for (int j = 0; j < 4; j++) acc[i][j] = (f32x4){0.f,0.f,0.f,0.f};

#pragma unroll
    for (int ks = 0; ks < KV / 32; ks++) {
        bf16x8 ah[4], al[4], bh[4], bl[4];
#pragma unroll
        for (int i = 0; i < 4; i++) {
            ah[i] = *(const bf16x8*)(lds_hi + (i*16 + l15) * AS + ks*32 + grp*8);
            al[i] = *(const bf16x8*)(lds_lo + (i*16 + l15) * AS + ks*32 + grp*8);
        }
#pragma unroll
        for (int j = 0; j < 4; j++) {
            bh[j] = *(const bf16x8*)(wth + (size_t)(cw + j*16 + l15) * KV + ks*32 + grp*8);
            bl[j] = *(const bf16x8*)(wtl + (size_t)(cw + j*16 + l15) * KV + ks*32 + grp*8);
        }
#pragma unroll
        for (int i = 0; i < 4; i++)
#pragma unroll
            for (int j = 0; j < 4; j++) {
                acc[i][j] = __builtin_amdgcn_mfma_f32_16x16x32_bf16(ah[i], bl[j], acc[i][j], 0, 0, 0);
                acc[i][j] = __builtin_amdgcn_mfma_f32_16x16x32_bf16(al[i], bh[j], acc[i][j], 0, 0, 0);
                acc[i][j] = __builtin_amdgcn_mfma_f32_16x16x32_bf16(ah[i], bh[j], acc[i][j], 0, 0, 0);
            }
    }

    __syncthreads();
#pragma unroll
    for (int i = 0; i < 4; i++)
#pragma unroll
        for (int j = 0; j < 4; j++)
#pragma unroll
            for (int r = 0; r < 4; r++) {
                int row = r0 + i*16 + grp*4 + r;
                int col = cw + j*16 + l15;
                if (row < N_NODES) {
                    float v = acc[i][j][r] + bias[col];
                    Out[(long)row * 256 + col] = lrelu(v, 0.01f);
                }
            }
}

// ---------------- hi/lo MFMA MLP layer 3: Xt[24][N] = leaky(A @ W3^T + bias) ---------
__global__ __launch_bounds__(256) void mlp_mfma24_hilo(
    const float* __restrict__ A,
    const unsigned short* __restrict__ wth, const unsigned short* __restrict__ wtl,
    const float* __restrict__ bias, float* __restrict__ XtOut)
{
    constexpr int KV = 256, AS = 264;
    __shared__ unsigned short lds_hi[64 * AS];
    __shared__ unsigned short lds_lo[64 * AS];
    const int t = threadIdx.x;
    const int r0 = blockIdx.x * 64;
    const int wv = t >> 6, lane = t & 63;
    const int l15 = lane & 15, grp = lane >> 4;

    constexpr int cpr = KV / 8;
    for (int c = t; c < 64 * cpr; c += 256) {
        int row = c / cpr, kc = c % cpr;
        int gr = r0 + row;
        float4 v0 = make_float4(0,0,0,0), v1 = v0;
        if (gr < N_NODES) {
            v0 = *(const float4*)(A + (long)gr * KV + kc * 8);
            v1 = *(const float4*)(A + (long)gr * KV + kc * 8 + 4);
        }
        float vs[8] = {v0.x,v0.y,v0.z,v0.w,v1.x,v1.y,v1.z,v1.w};
        unsigned short* ph = lds_hi + row * AS + kc * 8;
        unsigned short* pl = lds_lo + row * AS + kc * 8;
#pragma unroll
        for (int j = 0; j < 8; j++) {
            unsigned short hi = f2bf(vs[j]);
            ph[j] = hi;
            pl[j] = f2bf(vs[j] - bf2f(hi));
        }
    }
    __syncthreads();

    f32x4 acc[2] = {(f32x4){0.f,0.f,0.f,0.f}, (f32x4){0.f,0.f,0.f,0.f}};
#pragma unroll
    for (int ks = 0; ks < KV / 32; ks++) {
        bf16x8 ah = *(const bf16x8*)(lds_hi + (wv*16 + l15) * AS + ks*32 + grp*8);
        bf16x8 al = *(const bf16x8*)(lds_lo + (wv*16 + l15) * AS + ks*32 + grp*8);
#pragma unroll
        for (int j = 0; j < 2; j++) {
            bf16x8 bh = *(const bf16x8*)(wth + (size_t)(j*16 + l15) * KV + ks*32 + grp*8);
            bf16x8 bl = *(const bf16x8*)(wtl + (size_t)(j*16 + l15) * KV + ks*32 + grp*8);
            acc[j] = __builtin_amdgcn_mfma_f32_16x16x32_bf16(ah, bl, acc[j], 0, 0, 0);
            acc[j] = __builtin_amdgcn_mfma_f32_16x16x32_bf16(al, bh, acc[j], 0, 0, 0);
            acc[j] = __builtin_amdgcn_mfma_f32_16x16x32_bf16(ah, bh, acc[j], 0, 0, 0);
        }
    }

    __syncthreads();
    float* ldsf = (float*)lds_hi;               // [64][25] f32 out-stage
#pragma unroll
    for (int j = 0; j < 2; j++)
#pragma unroll
        for (int r = 0; r < 4; r++) {
            int cl = j*16 + l15;
            if (cl < 24) {
                int rl = wv*16 + grp*4 + r;
                float v = acc[j][r] + bias[cl];
                ldsf[rl * 25 + cl] = lrelu(v, 0.01f);
            }
        }
    __syncthreads();
    int n = t & 63, c0 = t >> 6;
    int gr = r0 + n;
    if (gr < N_NODES)
        for (int c = c0; c < 24; c += 4)
            XtOut[(long)c * N_NODES + gr] = ldsf[n * 25 + c];
}

// ---------------- BN stats over channel-major layout ----------------
__global__ void bn_stats_t(const float* __restrict__ Xt,
                           float* __restrict__ gsum, float* __restrict__ gsq)
{
    int ch = blockIdx.x, part = blockIdx.y, t = threadIdx.x;
    const float* p = Xt + (long)ch * N_NODES;
    float s = 0.f, q = 0.f;
    for (long i = (long)part * 25000 + t * 4; i < (long)(part + 1) * 25000; i += 1024) {
        float4 v = *(const float4*)(p + i);
        s += v.x + v.y + v.z + v.w;
        q += v.x*v.x + v.y*v.y + v.z*v.z + v.w*v.w;
    }
#pragma unroll
    for (int m = 1; m < 64; m <<= 1) {
        s += __shfl_xor(s, m, 64);
        q += __shfl_xor(q, m, 64);
    }
    __shared__ float ls[4], lq[4];
    int wid = t >> 6;
    if ((t & 63) == 0) { ls[wid] = s; lq[wid] = q; }
    __syncthreads();
    if (t == 0) {
        atomicAdd(gsum + ch, ls[0] + ls[1] + ls[2] + ls[3]);
        atomicAdd(gsq  + ch, lq[0] + lq[1] + lq[2] + lq[3]);
    }
}

// ---------------- reduce per-block partial stats ----------------
__global__ __launch_bounds__(256) void bn_reduce(
    const float* __restrict__ ps, const float* __restrict__ pq,
    float* __restrict__ gsum, float* __restrict__ gsq, int C)
{
    int g = blockIdx.x;
    int t = threadIdx.x;
    float s = 0.f, q = 0.f;
    for (int b = t; b < DG4; b += 256) {
        s += ps[g * DG4 + b];
        q += pq[g * DG4 + b];
    }
    __shared__ float ls[256], lq[256];
    ls[t] = s; lq[t] = q; __syncthreads();
    for (int o = 128; o > 0; o >>= 1) {
        if (t < o) { ls[t] += ls[t + o]; lq[t] += lq[t + o]; }
        __syncthreads();
    }
    if (t == 0) { gsum[C + g] = ls[0]; gsq[C + g] = lq[0]; }
}

// ---------------- densenet layer, 4 nodes/thread, float4 IO ----------------
__global__ __launch_bounds__(64) void dense_conv_t4(
    float* __restrict__ Xt, int C,
    const float* __restrict__ W, int WS,
    const float* __restrict__ gamma, const float* __restrict__ beta,
    const float* __restrict__ gsum, const float* __restrict__ gsq,
    float* __restrict__ ps, float* __restrict__ pq)
{
    __shared__ float w_lds[12 * 132];
    __shared__ float a_lds[132], b_lds[132];
    int t = threadIdx.x;
    for (int c = t; c < C; c += 64) {
        float mu  = gsum[c] * (1.f / N_NODES);
        float var = gsq[c]  * (1.f / N_NODES) - mu * mu;
        float A = rsqrtf(var + 1e-5f) * gamma[c];
        a_lds[c] = A;
        b_lds[c] = beta[c] - mu * A;
    }
#pragma unroll
    for (int g = 0; g < 12; g++)
        for (int c = t; c < C; c += 64)
            w_lds[g * 132 + c] = W[g * WS + c];
    __syncthreads();

    int tid = blockIdx.x * 64 + t;
    bool valid = (tid < N_NODES / 4);
    long n4 = (long)(valid ? tid : 0) * 4;
    const float* xp = Xt + n4;

    float4 acc[12];
#pragma unroll
    for (int g = 0; g < 12; g++) acc[g] = make_float4(0.f,0.f,0.f,0.f);

    float4 v[12], vn[12];
#pragma unroll
    for (int j = 0; j < 12; j++) v[j] = *(const float4*)(xp + (long)j * N_NODES);
    for (int c0 = 0; c0 < C; c0 += 12) {
        if (c0 + 12 < C) {
#pragma unroll
            for (int j = 0; j < 12; j++)
                vn[j] = *(const float4*)(xp + (long)(c0 + 12 + j) * N_NODES);
        }
#pragma unroll
        for (int j = 0; j < 12; j++) {
            int ch = c0 + j;
            float Ac = a_lds[ch], Bc = b_lds[ch];
            float ux = lrelu(Ac * v[j].x + Bc, 0.01f);
            float uy = lrelu(Ac * v[j].y + Bc, 0.01f);
            float uz = lrelu(Ac * v[j].z + Bc, 0.01f);
            float uw = lrelu(Ac * v[j].w + Bc, 0.01f);
#pragma unroll
            for (int g = 0; g < 12; g++) {
                float wv = w_lds[g * 132 + ch];
                acc[g].x += ux * wv; acc[g].y += uy * wv;
                acc[g].z += uz * wv; acc[g].w += uw * wv;
            }
        }
#pragma unroll
        for (int j = 0; j < 12; j++) v[j] = vn[j];
    }
    if (valid) {
#pragma unroll
        for (int g = 0; g < 12; g++)
            *(float4*)(Xt + (long)(C + g) * N_NODES + n4) = acc[g];
    }
    float sv[12], qv[12];
#pragma unroll
    for (int g = 0; g < 12; g++) {
        float4 a = valid ? acc[g] : make_float4(0.f,0.f,0.f,0.f);
        sv[g] = a.x + a.y + a.z + a.w;
        qv[g] = a.x*a.x + a.y*a.y + a.z*a.z + a.w*a.w;
    }
#pragma unroll
    for (int m = 1; m < 64; m <<= 1)
#pragma unroll
        for (int g = 0; g < 12; g++) {
            sv[g] += __shfl_xor(sv[g], m, 64);
            qv[g] += __shfl_xor(qv[g], m, 64);
        }
    if (t == 0) {
#pragma unroll
        for (int g = 0; g < 12; g++) {
            ps[g * DG4 + blockIdx.x] = sv[g];
            pq[g * DG4 + blockIdx.x] = qv[g];
        }
    }
}

// ---------------- GAT GEMM (f32-exact) + fused scores + bf16 H (stride 64) -------
template<int F>
__global__ __launch_bounds__(256) void gat_gemm(
    const float* __restrict__ A, const float* __restrict__ B,
    const float* __restrict__ avec, int K,
    unsigned short* __restrict__ Hb, float* __restrict__ sd, float* __restrict__ ss)
{
    __shared__ float At[16 * 68];
    __shared__ float Bt[16 * 64];
    __shared__ float ad[64], as_[64];
    const int t  = threadIdx.x;
    const int r0 = blockIdx.x * 64;
    const int tx = t & 15, ty = t >> 4;
    if (t < 64) {
        ad[t]  = (t < F) ? avec[t]     : 0.f;
        as_[t] = (t < F) ? avec[F + t] : 0.f;
    }

    float acc[4][4];
#pragma unroll
    for (int i = 0; i < 4; i++)
#pragma unroll
        for (int j = 0; j < 4; j++) acc[i][j] = 0.f;

    for (int k0 = 0; k0 < K; k0 += 16) {
        {   // stage A (channel-major, coalesced)
            int kk = t >> 4, rq = t & 15;
            float4 v = make_float4(0.f,0.f,0.f,0.f);
            if (k0 + kk < K)
                v = *(const float4*)(A + (long)(k0 + kk) * N_NODES + r0 + rq * 4);
            *(float4*)(At + kk * 68 + rq * 4) = v;
        }
        for (int i = t; i < 16 * 64; i += 256) {   // stage B [16][64]
            int kk = i >> 6, mq = i & 63;
            float v = 0.f;
            if (k0 + kk < K && mq < F) v = B[(long)(k0 + kk) * F + mq];
            Bt[kk * 64 + mq] = v;
        }
        __syncthreads();
#pragma unroll
        for (int kk = 0; kk < 16; kk++) {
            float4 av = *(const float4*)(At + kk * 68 + ty * 4);
            float4 bv = *(const float4*)(Bt + kk * 64 + tx * 4);
            float a_[4] = {av.x, av.y, av.z, av.w};
            float b_[4] = {bv.x, bv.y, bv.z, bv.w};
#pragma unroll
            for (int i = 0; i < 4; i++)
#pragma unroll
                for (int j = 0; j < 4; j++)
                    acc[i][j] += a_[i] * b_[j];
        }
        __syncthreads();
    }

#pragma unroll
    for (int i = 0; i < 4; i++) {
        int row = r0 + ty * 4 + i;
        float pd = 0.f, pq_ = 0.f;
#pragma unroll
        for (int j = 0; j < 4; j++) {
            int col = tx * 4 + j;
            pd  += acc[i][j] * ad[col];
            pq_ += acc[i][j] * as_[col];
        }
#pragma unroll
        for (int m = 1; m < 16; m <<= 1) {
            pd  += __shfl_xor(pd,  m, 64);
            pq_ += __shfl_xor(pq_, m, 64);
        }
        if (row < N_NODES) {
            if (tx == 0) { sd[row] = pd; ss[row] = pq_; }
            if (tx * 4 < F) {
                ushort4_t u;
#pragma unroll
                for (int j = 0; j < 4; j++) u[j] = f2bf(acc[i][j]);
                *(ushort4_t*)(Hb + (long)row * 64 + tx * 4) = u;   // stride 64 -> 1 line/row
            }
        }
    }
}

// ---------------- fused GAT softmax+aggregate over CSR ----------------
// Block = 64 consecutive nodes (4 waves x 16). Per node: wave computes max, exp,
// den, and weighted sum of bf16 H rows (stride 64 = one 128B line each).
// Output staged in LDS, written channel-major coalesced.
template<int F>
__global__ __launch_bounds__(256) void gat_aggregate2(
    const int* __restrict__ rstart, const int* __restrict__ csr_src,
    const float* __restrict__ sd, const float* __restrict__ ss,
    const unsigned short* __restrict__ Hb,
    const float* __restrict__ bias, float* __restrict__ outT)
{
    __shared__ float tile[64 * (F + 1)];
    const int t = threadIdx.x;
    const int wid = t >> 6, lane = t & 63;
    const long n0 = (long)blockIdx.x * 64;

#pragma unroll 1
    for (int k = 0; k < 16; k++) {
        long node = n0 + wid * 16 + k;
        float res = 0.f;
        if (node < N_NODES) {
            int st = rstart[node], en = rstart[node + 1];
            int deg = en - st;
            float sdn = sd[node];
            float acc = 0.f, dsum = 0.f;
            if (deg <= 64) {                      // fast path: cache v/src in regs
                int sj = 0; float v = -3.4e38f;
                if (lane < deg) {
                    sj = csr_src[st + lane];
                    v = lrelu(sdn + ss[sj], 0.2f);
                }
                float m = v;
#pragma unroll
                for (int o = 1; o < 64; o <<= 1) m = fmaxf(m, __shfl_xor(m, o, 64));
                float p = (lane < deg) ? __expf(v - m) : 0.f;
                dsum = p;
                for (int j = 0; j < deg; j++) {
                    float a = __shfl(p, j, 64);
                    int   s = __shfl(sj, j, 64);
                    if (lane < F) acc += a * bf2f(Hb[(long)s * 64 + lane]);
                }
            } else {                              // generic chunked path
                float m = -3.4e38f;
                for (int base = st; base < en; base += 64) {
                    int cnt = min(64, en - base);
                    float v = -3.4e38f;
                    if (lane < cnt) {
                        int s = csr_src[base + lane];
                        v = lrelu(sdn + ss[s], 0.2f);
                    }
#pragma unroll
                    for (int o = 1; o < 64; o <<= 1) v = fmaxf(v, __shfl_xor(v, o, 64));
                    m = fmaxf(m, v);
                }
                for (int base = st; base < en; base += 64) {
                    int cnt = min(64, en - base);
                    float p = 0.f; int sj = 0;
                    if (lane < cnt) {
                        sj = csr_src[base + lane];
                        float v = lrelu(sdn + ss[sj], 0.2f);
                        p = __expf(v - m);
                    }
                    dsum += p;
                    for (int j = 0; j < cnt; j++) {
                        float a = __shfl(p, j, 64);
                        int   s = __shfl(sj, j, 64);
                        if (lane < F) acc += a * bf2f(Hb[(long)s * 64 + lane]);
                    }
                }
            }
#pragma unroll
            for (int o = 1; o < 64; o <<= 1) dsum += __shfl_xor(dsum, o, 64);
            res = acc / (dsum + 1e-16f);
        }
        if (lane < F) tile[(wid * 16 + k) * (F + 1) + lane] = res + bias[lane];
    }
    __syncthreads();
    for (int idx = t; idx < F * 64; idx += 256) {
        int c = idx / 64, i = idx % 64;
        long n = n0 + i;
        if (n < N_NODES) outT[(long)c * N_NODES + n] = tile[i * (F + 1) + c];
    }
}

// ---------------- final transpose [132][N] -> [N,132] ----------------
__global__ __launch_bounds__(256) void transpose_out(const float* __restrict__ Xt,
                                                     float* __restrict__ out)
{
    __shared__ float tile[64 * 133];
    int t = threadIdx.x;
    long n0 = (long)blockIdx.x * 64;
    int lane = t & 63, cq = t >> 6;
    for (int c = cq; c < 132; c += 4) {
        long n = n0 + lane;
        float v = (n < N_NODES) ? Xt[(long)c * N_NODES + n] : 0.f;
        tile[lane * 133 + c] = v;
    }
    __syncthreads();
    for (int idx = t; idx < 64 * 132; idx += 256) {
        int r = idx / 132, c = idx % 132;
        long n = n0 + r;
        if (n < N_NODES) out[n * 132 + c] = tile[r * 133 + c];
    }
}

// ---------------- CSR build ----------------
__global__ void hist_kernel(const int* __restrict__ dst, int* __restrict__ deg)
{
    for (long e = (long)blockIdx.x * 256 + threadIdx.x; e < N_EDGES; e += (long)gridDim.x * 256)
        atomicAdd(deg + dst[e], 1);
}

__global__ void scan1(const int* __restrict__ deg, int* __restrict__ rtmp, int* __restrict__ parts)
{
    __shared__ int ls[256];
    int t = threadIdx.x;
    long i = (long)blockIdx.x * 256 + t;
    int v = (i < N_NODES) ? deg[i] : 0;
    ls[t] = v; __syncthreads();
    for (int o = 1; o < 256; o <<= 1) {
        int y = (t >= o) ? ls[t - o] : 0;
        __syncthreads();
        ls[t] += y;
        __syncthreads();
    }
    if (i < N_NODES) rtmp[i] = ls[t] - v;
    if (t == 255) parts[blockIdx.x] = ls[255];
}

__global__ void scan2(int* __restrict__ parts, int nb, int* __restrict__ total_out)
{
    __shared__ int ls[512];
    int t = threadIdx.x;
    int v = (t < nb) ? parts[t] : 0;
    ls[t] = v; __syncthreads();
    for (int o = 1; o < 512; o <<= 1) {
        int y = (t >= o) ? ls[t - o] : 0;
        __syncthreads();
        ls[t] += y;
        __syncthreads();
    }
    if (t < nb) parts[t] = ls[t] - v;
    if (t == 0) total_out[0] = ls[511];
}

__global__ void scan3(const int* __restrict__ rtmp, const int* __restrict__ parts,
                      int* __restrict__ rstart, int* __restrict__ cursor)
{
    long i = (long)blockIdx.x * 256 + threadIdx.x;
    if (i < N_NODES) {
        int v = rtmp[i] + parts[i >> 8];
        rstart[i] = v;
        cursor[i] = v;
    }
}

// stores SRC VALUES in dst-sorted CSR order (not edge ids)
__global__ void scatter_k(const int* __restrict__ src, const int* __restrict__ dst,
                          int* __restrict__ cursor, int* __restrict__ csr_src)
{
    for (long e = (long)blockIdx.x * 256 + threadIdx.x; e < N_EDGES; e += (long)gridDim.x * 256) {
        int pos = atomicAdd(cursor + dst[e], 1);
        csr_src[pos] = src[e];
    }
}

// ---------------- host helpers ----------------
static void run_dense_block_t(hipStream_t stream, float* Xt, int C0,
                              const float* convW, int WS,
                              const float* gamma, const float* beta,
                              float* gsum, float* gsq, float* ps, float* pq)
{
    hipMemsetAsync(gsum, 0, 264 * sizeof(float), stream);
    bn_stats_t<<<dim3(C0, 4), 256, 0, stream>>>(Xt, gsum, gsq);
    for (int i = 0; i < 6; i++) {
        int C = C0 + 12 * i;
        dense_conv_t4<<<DG4, 64, 0, stream>>>(Xt, C, convW + (size_t)i * 12 * WS, WS,
                                              gamma + (size_t)i * WS, beta + (size_t)i * WS,
                                              gsum, gsq, ps, pq);
        if (i < 5)
            bn_reduce<<<12, 256, 0, stream>>>(ps, pq, gsum, gsq, C);
    }
}

template<int F>
static void run_gat(hipStream_t stream, const float* XtIn, int K,
                    const float* W, const float* avec, const float* bias,
                    unsigned short* Hb, float* outT,
                    float* sd, float* ss, const int* rstart, const int* csr_src)
{
    gat_gemm<F><<<GG, 256, 0, stream>>>(XtIn, W, avec, K, Hb, sd, ss);
    gat_aggregate2<F><<<GG, 256, 0, stream>>>(rstart, csr_src, sd, ss, Hb, bias, outT);
}

extern "C" void kernel_launch(void* const* d_in, const int* in_sizes, int n_in,
                              void* d_out, int out_size, void* d_ws, size_t ws_size,
                              hipStream_t stream)
{
    const float* x     = (const float*)d_in[0];
    const int*   src   = (const int*)d_in[1];
    const int*   dst   = (const int*)d_in[2];
    const float* w1    = (const float*)d_in[3];
    const float* b1    = (const float*)d_in[4];
    const float* w2    = (const float*)d_in[5];
    const float* b2    = (const float*)d_in[6];
    const float* w3    = (const float*)d_in[7];
    const float* b3    = (const float*)d_in[8];
    const float* conv1 = (const float*)d_in[9];
    const float* bn1g  = (const float*)d_in[10];
    const float* bn1b  = (const float*)d_in[11];
    const float* g1w   = (const float*)d_in[12];
    const float* g1a   = (const float*)d_in[13];
    const float* g1b   = (const float*)d_in[14];
    const float* conv2 = (const float*)d_in[15];
    const float* bn2g  = (const float*)d_in[16];
    const float* bn2b  = (const float*)d_in[17];
    const float* g2w   = (const float*)d_in[18];
    const float* g2a   = (const float*)d_in[19];
    const float* g2b   = (const float*)d_in[20];
    const float* conv3 = (const float*)d_in[21];
    const float* bn3g  = (const float*)d_in[22];
    const float* bn3b  = (const float*)d_in[23];
    float* out = (float*)d_out;

    char* ws = (char*)d_ws;
    size_t off = 0;
    auto alloc = [&](size_t bytes) -> void* {
        void* p = ws + off;
        off += (bytes + 255) & ~(size_t)255;
        return p;
    };
    float*    h      = (float*)alloc((size_t)N_NODES * 256 * 4); // MLP f32; later Hb + Xt3
    float*    Xt1    = (float*)alloc((size_t)96  * N_NODES * 4);
    float*    Xt2    = (float*)alloc((size_t)120 * N_NODES * 4);
    int*      csr_src= (int*)alloc((size_t)N_EDGES * 4);
    int*      deg    = (int*)alloc((size_t)N_NODES * 4);
    int*      rtmp   = (int*)alloc((size_t)N_NODES * 4);
    int*      rstart = (int*)alloc((size_t)(N_NODES + 1) * 4);
    int*      cursor = (int*)alloc((size_t)N_NODES * 4);
    int*      parts  = (int*)alloc(2048);
    float*    sd     = (float*)alloc((size_t)N_NODES * 4);
    float*    ss     = (float*)alloc((size_t)N_NODES * 4);
    float*    gsum   = (float*)alloc(264 * 4);
    float*    gsq    = gsum + 132;
    float*    ps     = (float*)alloc((size_t)12 * DG4 * 4);
    float*    pq     = (float*)alloc((size_t)12 * DG4 * 4);
    unsigned short* wt1h = (unsigned short*)alloc(256 * 64  * 2);
    unsigned short* wt1l = (unsigned short*)alloc(256 * 64  * 2);
    unsigned short* wt2h = (unsigned short*)alloc(256 * 256 * 2);
    unsigned short* wt2l = (unsigned short*)alloc(256 * 256 * 2);
    unsigned short* wt3h = (unsigned short*)alloc(32  * 256 * 2);
    unsigned short* wt3l = (unsigned short*)alloc(32  * 256 * 2);

    // overlays in h (102.4 MB), dead after the MLP:
    unsigned short* Hb  = (unsigned short*)h;            // [N][64] bf16 = 12.8 MB (128B rows)
    float* Xt3 = (float*)((char*)h + (size_t)16 * 1024 * 1024); // [132][N] f32 = 52.8 MB

    // ---- CSR by dst (shared by both GATs), payload = src values ----
    hipMemsetAsync(deg, 0, (size_t)N_NODES * 4, stream);
    hist_kernel<<<2048, 256, 0, stream>>>(dst, deg);
    scan1<<<NODE_GRID, 256, 0, stream>>>(deg, rtmp, parts);
    scan2<<<1, 512, 0, stream>>>(parts, NODE_GRID, rstart + N_NODES);
    scan3<<<NODE_GRID, 256, 0, stream>>>(rtmp, parts, rstart, cursor);
    scatter_k<<<2048, 256, 0, stream>>>(src, dst, cursor, csr_src);

    // ---- weight prep (f32 -> transposed hi/lo bf16) ----
    cvt_wT_split<<<(256 * 64  + 255) / 256, 256, 0, stream>>>(w1, wt1h, wt1l, 64,  256, 256);
    cvt_wT_split<<<(256 * 256 + 255) / 256, 256, 0, stream>>>(w2, wt2h, wt2l, 256, 256, 256);
    cvt_wT_split<<<(32  * 256 + 255) / 256, 256, 0, stream>>>(w3, wt3h, wt3l, 256, 24,  32);

    // ---- MLP (hi/lo bf16 MFMA, ~f32 precision, f32 intermediates) ----
    mlp_mfma_hilo<64> <<<GG, 256, 0, stream>>>(x, wt1h, wt1l, b1, h);
    mlp_mfma_hilo<256><<<GG, 256, 0, stream>>>(h, wt2h, wt2l, b2, h);   // in-place
    mlp_mfma24_hilo<<<GG, 256, 0, stream>>>(h, wt3h, wt3l, b3, Xt1);

    // ---- dense block 1 (24 -> 96, channel-major) ----
    run_dense_block_t(stream, Xt1, 24, conv1, 84, bn1g, bn1b, gsum, gsq, ps, pq);

    // ---- GAT 1 (96 -> 48), output transposed into Xt2 rows 0..47 ----
    run_gat<48>(stream, Xt1, 96, g1w, g1a, g1b, Hb, Xt2, sd, ss, rstart, csr_src);

    // ---- dense block 2 (48 -> 120) ----
    run_dense_block_t(stream, Xt2, 48, conv2, 108, bn2g, bn2b, gsum, gsq, ps, pq);

    // ---- GAT 2 (120 -> 60), output transposed into Xt3 rows 0..59 ----
    run_gat<60>(stream, Xt2, 120, g2w, g2a, g2b, Hb, Xt3, sd, ss, rstart, csr_src);

    // ---- dense block 3 (60 -> 132) ----
    run_dense_block_t(stream, Xt3, 60, conv3, 120, bn3g, bn3b, gsum, gsq, ps, pq);

    // ---- final transpose to row-major d_out ----
    transpose_out<<<GG, 256, 0, stream>>>(Xt3, out);
}

// Round 8
// 1152.166 us; speedup vs baseline: 1.3871x; 1.0860x over previous
//
#include <hip/hip_runtime.h>
#include <math.h>

#define N_NODES 100000
#define N_EDGES 1600000

static constexpr int GG = (N_NODES + 63) / 64;          // 1563
static constexpr int NODE_GRID = (N_NODES + 255) / 256; // 391
static constexpr int NB = (N_NODES + 255) / 256;        // 391 dense blocks (256 thr)

typedef __attribute__((ext_vector_type(8))) short          bf16x8;
typedef __attribute__((ext_vector_type(8))) unsigned short ushort8_t;
typedef __attribute__((ext_vector_type(4))) unsigned short ushort4_t;
typedef __attribute__((ext_vector_type(4))) float          f32x4;

__device__ __forceinline__ float lrelu(float v, float s){ return v >= 0.f ? v : v*s; }

__device__ __forceinline__ unsigned short f2bf(float f){
    unsigned u = __float_as_uint(f);
    unsigned r = (u + 0x7FFFu + ((u >> 16) & 1u)) >> 16;   // RNE
    return (unsigned short)r;
}
__device__ __forceinline__ float bf2f(unsigned short h){
    return __uint_as_float(((unsigned)h) << 16);
}

// ---------------- weight split: wt_hi/lo[n][k] = hi/lo bf16 of w[k][n] ----------------
__global__ void cvt_wT_split(const float* __restrict__ w,
                             unsigned short* __restrict__ whi,
                             unsigned short* __restrict__ wlo,
                             int K, int Nsrc, int Npad)
{
    int idx = blockIdx.x * 256 + threadIdx.x;
    if (idx >= Npad * K) return;
    int n = idx / K, k = idx % K;
    float v = (n < Nsrc) ? w[(long)k * Nsrc + n] : 0.f;
    unsigned short hi = f2bf(v);
    whi[idx] = hi;
    wlo[idx] = f2bf(v - bf2f(hi));
}

// ---------------- hi/lo MFMA MLP layer: Out[f32 N x 256] = leaky(A @ W^T + bias) ------
template<int KV>
__global__ __launch_bounds__(256) void mlp_mfma_hilo(
    const float* __restrict__ A,
    const unsigned short* __restrict__ wth, const unsigned short* __restrict__ wtl,
    const float* __restrict__ bias, float* __restrict__ Out)
{
    constexpr int AS = KV + 8;
    __shared__ unsigned short lds_hi[64 * AS];
    __shared__ unsigned short lds_lo[64 * AS];
    const int t = threadIdx.x;
    const int r0 = blockIdx.x * 64;
    const int wv = t >> 6, lane = t & 63;
    const int l15 = lane & 15, grp = lane >> 4;
    const int cw = wv * 64;

    constexpr int cpr = KV / 8;
    for (int c = t; c < 64 * cpr; c += 256) {
        int row = c / cpr, kc = c % cpr;
        int gr = r0 + row;
        float4 v0 = make_float4(0,0,0,0), v1 = v0;
        if (gr < N_NODES) {
            v0 = *(const float4*)(A + (long)gr * KV + kc * 8);
            v1 = *(const float4*)(A + (long)gr * KV + kc * 8 + 4);
        }
        float vs[8] = {v0.x,v0.y,v0.z,v0.w,v1.x,v1.y,v1.z,v1.w};
        unsigned short* ph = lds_hi + row * AS + kc * 8;
        unsigned short* pl = lds_lo + row * AS + kc * 8;
#pragma unroll
        for (int j = 0; j < 8; j++) {
            unsigned short hi = f2bf(vs[j]);
            ph[j] = hi;
            pl[j] = f2bf(vs[j] - bf2f(hi));
        }
    }
    __syncthreads();

    f32x4 acc[4][4];
#pragma unroll
    for (int i = 0; i < 4; i++)
#pragma unroll
        for (int j = 0; j < 4; j++) acc[i][j] = (f32x4){0.f,0.f,0.f,0.f};

#pragma unroll
    for (int ks = 0; ks < KV / 32; ks++) {
        bf16x8 ah[4], al[4], bh[4], bl[4];
#pragma unroll
        for (int i = 0; i < 4; i++) {
            ah[i] = *(const bf16x8*)(lds_hi + (i*16 + l15) * AS + ks*32 + grp*8);
            al[i] = *(const bf16x8*)(lds_lo + (i*16 + l15) * AS + ks*32 + grp*8);
        }
#pragma unroll
        for (int j = 0; j < 4; j++) {
            bh[j] = *(const bf16x8*)(wth + (size_t)(cw + j*16 + l15) * KV + ks*32 + grp*8);
            bl[j] = *(const bf16x8*)(wtl + (size_t)(cw + j*16 + l15) * KV + ks*32 + grp*8);
        }
#pragma unroll
        for (int i = 0; i < 4; i++)
#pragma unroll
            for (int j = 0; j < 4; j++) {
                acc[i][j] = __builtin_amdgcn_mfma_f32_16x16x32_bf16(ah[i], bl[j], acc[i][j], 0, 0, 0);
                acc[i][j] = __builtin_amdgcn_mfma_f32_16x16x32_bf16(al[i], bh[j], acc[i][j], 0, 0, 0);
                acc[i][j] = __builtin_amdgcn_mfma_f32_16x16x32_bf16(ah[i], bh[j], acc[i][j], 0, 0, 0);
            }
    }

    __syncthreads();
#pragma unroll
    for (int i = 0; i < 4; i++)
#pragma unroll
        for (int j = 0; j < 4; j++)
#pragma unroll
            for (int r = 0; r < 4; r++) {
                int row = r0 + i*16 + grp*4 + r;
                int col = cw + j*16 + l15;
                if (row < N_NODES) {
                    float v = acc[i][j][r] + bias[col];
                    Out[(long)row * 256 + col] = lrelu(v, 0.01f);
                }
            }
}

// ---------------- hi/lo MFMA MLP layer 3: Xt[24][N] = leaky(A @ W3^T + bias) ---------
__global__ __launch_bounds__(256) void mlp_mfma24_hilo(
    const float* __restrict__ A,
    const unsigned short* __restrict__ wth, const unsigned short* __restrict__ wtl,
    const float* __restrict__ bias, float* __restrict__ XtOut)
{
    constexpr int KV = 256, AS = 264;
    __shared__ unsigned short lds_hi[64 * AS];
    __shared__ unsigned short lds_lo[64 * AS];
    const int t = threadIdx.x;
    const int r0 = blockIdx.x * 64;
    const int wv = t >> 6, lane = t & 63;
    const int l15 = lane & 15, grp = lane >> 4;

    constexpr int cpr = KV / 8;
    for (int c = t; c < 64 * cpr; c += 256) {
        int row = c / cpr, kc = c % cpr;
        int gr = r0 + row;
        float4 v0 = make_float4(0,0,0,0), v1 = v0;
        if (gr < N_NODES) {
            v0 = *(const float4*)(A + (long)gr * KV + kc * 8);
            v1 = *(const float4*)(A + (long)gr * KV + kc * 8 + 4);
        }
        float vs[8] = {v0.x,v0.y,v0.z,v0.w,v1.x,v1.y,v1.z,v1.w};
        unsigned short* ph = lds_hi + row * AS + kc * 8;
        unsigned short* pl = lds_lo + row * AS + kc * 8;
#pragma unroll
        for (int j = 0; j < 8; j++) {
            unsigned short hi = f2bf(vs[j]);
            ph[j] = hi;
            pl[j] = f2bf(vs[j] - bf2f(hi));
        }
    }
    __syncthreads();

    f32x4 acc[2] = {(f32x4){0.f,0.f,0.f,0.f}, (f32x4){0.f,0.f,0.f,0.f}};
#pragma unroll
    for (int ks = 0; ks < KV / 32; ks++) {
        bf16x8 ah = *(const bf16x8*)(lds_hi + (wv*16 + l15) * AS + ks*32 + grp*8);
        bf16x8 al = *(const bf16x8*)(lds_lo + (wv*16 + l15) * AS + ks*32 + grp*8);
#pragma unroll
        for (int j = 0; j < 2; j++) {
            bf16x8 bh = *(const bf16x8*)(wth + (size_t)(j*16 + l15) * KV + ks*32 + grp*8);
            bf16x8 bl = *(const bf16x8*)(wtl + (size_t)(j*16 + l15) * KV + ks*32 + grp*8);
            acc[j] = __builtin_amdgcn_mfma_f32_16x16x32_bf16(ah, bl, acc[j], 0, 0, 0);
            acc[j] = __builtin_amdgcn_mfma_f32_16x16x32_bf16(al, bh, acc[j], 0, 0, 0);
            acc[j] = __builtin_amdgcn_mfma_f32_16x16x32_bf16(ah, bh, acc[j], 0, 0, 0);
        }
    }

    __syncthreads();
    float* ldsf = (float*)lds_hi;               // [64][25] f32 out-stage
#pragma unroll
    for (int j = 0; j < 2; j++)
#pragma unroll
        for (int r = 0; r < 4; r++) {
            int cl = j*16 + l15;
            if (cl < 24) {
                int rl = wv*16 + grp*4 + r;
                float v = acc[j][r] + bias[cl];
                ldsf[rl * 25 + cl] = lrelu(v, 0.01f);
            }
        }
    __syncthreads();
    int n = t & 63, c0 = t >> 6;
    int gr = r0 + n;
    if (gr < N_NODES)
        for (int c = c0; c < 24; c += 4)
            XtOut[(long)c * N_NODES + gr] = ldsf[n * 25 + c];
}

// ---------------- BN stats over channel-major layout (initial C0 channels) -------
__global__ void bn_stats_t(const float* __restrict__ Xt,
                           float* __restrict__ gsum, float* __restrict__ gsq)
{
    int ch = blockIdx.x, part = blockIdx.y, t = threadIdx.x;
    const float* p = Xt + (long)ch * N_NODES;
    float s = 0.f, q = 0.f;
    for (long i = (long)part * 25000 + t * 4; i < (long)(part + 1) * 25000; i += 1024) {
        float4 v = *(const float4*)(p + i);
        s += v.x + v.y + v.z + v.w;
        q += v.x*v.x + v.y*v.y + v.z*v.z + v.w*v.w;
    }
#pragma unroll
    for (int m = 1; m < 64; m <<= 1) {
        s += __shfl_xor(s, m, 64);
        q += __shfl_xor(q, m, 64);
    }
    __shared__ float ls[4], lq[4];
    int wid = t >> 6;
    if ((t & 63) == 0) { ls[wid] = s; lq[wid] = q; }
    __syncthreads();
    if (t == 0) {
        atomicAdd(gsum + ch, ls[0] + ls[1] + ls[2] + ls[3]);
        atomicAdd(gsq  + ch, lq[0] + lq[1] + lq[2] + lq[3]);
    }
}

// ---------------- densenet layer: 256 thr, 1 node/thread, folded stats-reduce -------
// psq layout: ps = psq[layer*12 + g][NB], pq at offset 6*12*NB.
__global__ __launch_bounds__(256) void dense_conv2(
    float* __restrict__ Xt, int C, int C0, int layerIdx,
    const float* __restrict__ W, int WS,
    const float* __restrict__ gamma, const float* __restrict__ beta,
    const float* __restrict__ gsum, const float* __restrict__ gsq,
    float* __restrict__ psq)
{
    constexpr int QOFF = 6 * 12 * NB;
    __shared__ float w_lds[12 * 132];
    __shared__ float a_lds[132], b_lds[132];
    __shared__ float red[2][4][12];
    const int t = threadIdx.x;

    // BN coeffs: initial channels from gsum/gsq; grown channels reduced from psq
    for (int c = t; c < C; c += 256) {
        float s, q;
        if (c < C0) { s = gsum[c]; q = gsq[c]; }
        else {
            int lc = c - C0;
            int lj = lc / 12, g = lc % 12;
            const float* pp = psq + ((size_t)lj * 12 + g) * NB;
            const float* qq = pp + QOFF;
            s = 0.f; q = 0.f;
            for (int b = 0; b < NB; b++) { s += pp[b]; q += qq[b]; }
        }
        float mu  = s * (1.f / N_NODES);
        float var = q * (1.f / N_NODES) - mu * mu;
        float A = rsqrtf(var + 1e-5f) * gamma[c];
        a_lds[c] = A;
        b_lds[c] = beta[c] - mu * A;
    }
    for (int i = t; i < 12 * C; i += 256) {
        int g = i / C, c = i - g * C;
        w_lds[g * 132 + c] = W[g * WS + c];
    }
    __syncthreads();

    long n = (long)blockIdx.x * 256 + t;
    bool valid = (n < N_NODES);
    const float* xp = Xt + (valid ? n : 0);
    float acc[12];
#pragma unroll
    for (int g = 0; g < 12; g++) acc[g] = 0.f;

    float v[12], vn[12];
#pragma unroll
    for (int j = 0; j < 12; j++) v[j] = xp[(long)j * N_NODES];
    for (int c0 = 0; c0 < C; c0 += 12) {
        if (c0 + 12 < C) {
#pragma unroll
            for (int j = 0; j < 12; j++)
                vn[j] = xp[(long)(c0 + 12 + j) * N_NODES];
        }
#pragma unroll
        for (int j = 0; j < 12; j++) {
            int ch = c0 + j;
            float u = a_lds[ch] * v[j] + b_lds[ch];
            u = (u >= 0.f) ? u : 0.01f * u;
#pragma unroll
            for (int g = 0; g < 12; g++)
                acc[g] += u * w_lds[g * 132 + ch];
        }
#pragma unroll
        for (int j = 0; j < 12; j++) v[j] = vn[j];
    }
    if (valid) {
#pragma unroll
        for (int g = 0; g < 12; g++)
            Xt[(long)(C + g) * N_NODES + n] = acc[g];
    }

    if (layerIdx < 5) {   // last layer's stats are never used
        float sv[12], qv[12];
#pragma unroll
        for (int g = 0; g < 12; g++) {
            float a = valid ? acc[g] : 0.f;
            sv[g] = a; qv[g] = a * a;
        }
#pragma unroll
        for (int m = 1; m < 64; m <<= 1)
#pragma unroll
            for (int g = 0; g < 12; g++) {
                sv[g] += __shfl_xor(sv[g], m, 64);
                qv[g] += __shfl_xor(qv[g], m, 64);
            }
        int wid = t >> 6;
        if ((t & 63) == 0) {
#pragma unroll
            for (int g = 0; g < 12; g++) { red[0][wid][g] = sv[g]; red[1][wid][g] = qv[g]; }
        }
        __syncthreads();
        if (t < 12) {
            float s = red[0][0][t] + red[0][1][t] + red[0][2][t] + red[0][3][t];
            float q = red[1][0][t] + red[1][1][t] + red[1][2][t] + red[1][3][t];
            psq[((size_t)layerIdx * 12 + t) * NB + blockIdx.x] = s;
            psq[QOFF + ((size_t)layerIdx * 12 + t) * NB + blockIdx.x] = q;
        }
    }
}

// ---------------- GAT GEMM (f32-exact) + fused scores + bf16 H (stride 64) -------
template<int F>
__global__ __launch_bounds__(256) void gat_gemm(
    const float* __restrict__ A, const float* __restrict__ B,
    const float* __restrict__ avec, int K,
    unsigned short* __restrict__ Hb, float* __restrict__ sd, float* __restrict__ ss)
{
    __shared__ float At[16 * 68];
    __shared__ float Bt[16 * 64];
    __shared__ float ad[64], as_[64];
    const int t  = threadIdx.x;
    const int r0 = blockIdx.x * 64;
    const int tx = t & 15, ty = t >> 4;
    if (t < 64) {
        ad[t]  = (t < F) ? avec[t]     : 0.f;
        as_[t] = (t < F) ? avec[F + t] : 0.f;
    }

    float acc[4][4];
#pragma unroll
    for (int i = 0; i < 4; i++)
#pragma unroll
        for (int j = 0; j < 4; j++) acc[i][j] = 0.f;

    for (int k0 = 0; k0 < K; k0 += 16) {
        {   // stage A (channel-major, coalesced)
            int kk = t >> 4, rq = t & 15;
            float4 v = make_float4(0.f,0.f,0.f,0.f);
            if (k0 + kk < K)
                v = *(const float4*)(A + (long)(k0 + kk) * N_NODES + r0 + rq * 4);
            *(float4*)(At + kk * 68 + rq * 4) = v;
        }
        for (int i = t; i < 16 * 64; i += 256) {   // stage B [16][64]
            int kk = i >> 6, mq = i & 63;
            float v = 0.f;
            if (k0 + kk < K && mq < F) v = B[(long)(k0 + kk) * F + mq];
            Bt[kk * 64 + mq] = v;
        }
        __syncthreads();
#pragma unroll
        for (int kk = 0; kk < 16; kk++) {
            float4 av = *(const float4*)(At + kk * 68 + ty * 4);
            float4 bv = *(const float4*)(Bt + kk * 64 + tx * 4);
            float a_[4] = {av.x, av.y, av.z, av.w};
            float b_[4] = {bv.x, bv.y, bv.z, bv.w};
#pragma unroll
            for (int i = 0; i < 4; i++)
#pragma unroll
                for (int j = 0; j < 4; j++)
                    acc[i][j] += a_[i] * b_[j];
        }
        __syncthreads();
    }

#pragma unroll
    for (int i = 0; i < 4; i++) {
        int row = r0 + ty * 4 + i;
        float pd = 0.f, pq_ = 0.f;
#pragma unroll
        for (int j = 0; j < 4; j++) {
            int col = tx * 4 + j;
            pd  += acc[i][j] * ad[col];
            pq_ += acc[i][j] * as_[col];
        }
#pragma unroll
        for (int m = 1; m < 16; m <<= 1) {
            pd  += __shfl_xor(pd,  m, 64);
            pq_ += __shfl_xor(pq_, m, 64);
        }
        if (row < N_NODES) {
            if (tx == 0) { sd[row] = pd; ss[row] = pq_; }
            if (tx * 4 < F) {
                ushort4_t u;
#pragma unroll
                for (int j = 0; j < 4; j++) u[j] = f2bf(acc[i][j]);
                *(ushort4_t*)(Hb + (long)row * 64 + tx * 4) = u;   // stride 64 -> 1 line/row
            }
        }
    }
}

// ---------------- fused GAT softmax+aggregate over CSR (4x-unrolled gather) -------
template<int F>
__global__ __launch_bounds__(256) void gat_aggregate2(
    const int* __restrict__ rstart, const int* __restrict__ csr_src,
    const float* __restrict__ sd, const float* __restrict__ ss,
    const unsigned short* __restrict__ Hb,
    const float* __restrict__ bias, float* __restrict__ outT)
{
    __shared__ float tile[64 * (F + 1)];
    const int t = threadIdx.x;
    const int wid = t >> 6, lane = t & 63;
    const long n0 = (long)blockIdx.x * 64;

#pragma unroll 1
    for (int k = 0; k < 16; k++) {
        long node = n0 + wid * 16 + k;
        float res = 0.f;
        if (node < N_NODES) {
            int st = rstart[node], en = rstart[node + 1];
            int deg = en - st;
            float sdn = sd[node];
            float acc = 0.f, dsum = 0.f;
            if (deg <= 64) {                      // fast path: v/src cached in regs
                int sj = 0; float v = -3.4e38f;
                if (lane < deg) {
                    sj = csr_src[st + lane];
                    v = lrelu(sdn + ss[sj], 0.2f);
                }
                float m = v;
#pragma unroll
                for (int o = 1; o < 64; o <<= 1) m = fmaxf(m, __shfl_xor(m, o, 64));
                float p = (lane < deg) ? __expf(v - m) : 0.f;
                dsum = p;
                int j = 0;
                for (; j + 4 <= deg; j += 4) {   // 4 outstanding gathers
                    float a0 = __shfl(p, j, 64),   a1 = __shfl(p, j+1, 64);
                    float a2 = __shfl(p, j+2, 64), a3 = __shfl(p, j+3, 64);
                    int   s0 = __shfl(sj, j, 64),   s1 = __shfl(sj, j+1, 64);
                    int   s2 = __shfl(sj, j+2, 64), s3 = __shfl(sj, j+3, 64);
                    if (lane < F) {
                        float h0 = bf2f(Hb[(long)s0 * 64 + lane]);
                        float h1 = bf2f(Hb[(long)s1 * 64 + lane]);
                        float h2 = bf2f(Hb[(long)s2 * 64 + lane]);
                        float h3 = bf2f(Hb[(long)s3 * 64 + lane]);
                        acc += a0 * h0; acc += a1 * h1; acc += a2 * h2; acc += a3 * h3;
                    }
                }
                for (; j < deg; j++) {
                    float a = __shfl(p, j, 64);
                    int   s = __shfl(sj, j, 64);
                    if (lane < F) acc += a * bf2f(Hb[(long)s * 64 + lane]);
                }
            } else {                              // generic chunked path
                float m = -3.4e38f;
                for (int base = st; base < en; base += 64) {
                    int cnt = min(64, en - base);
                    float v = -3.4e38f;
                    if (lane < cnt) {
                        int s = csr_src[base + lane];
                        v = lrelu(sdn + ss[s], 0.2f);
                    }
#pragma unroll
                    for (int o = 1; o < 64; o <<= 1) v = fmaxf(v, __shfl_xor(v, o, 64));
                    m = fmaxf(m, v);
                }
                for (int base = st; base < en; base += 64) {
                    int cnt = min(64, en - base);
                    float p = 0.f; int sj = 0;
                    if (lane < cnt) {
                        sj = csr_src[base + lane];
                        float v = lrelu(sdn + ss[sj], 0.2f);
                        p = __expf(v - m);
                    }
                    dsum += p;
                    int j = 0;
                    for (; j + 4 <= cnt; j += 4) {
                        float a0 = __shfl(p, j, 64),   a1 = __shfl(p, j+1, 64);
                        float a2 = __shfl(p, j+2, 64), a3 = __shfl(p, j+3, 64);
                        int   s0 = __shfl(sj, j, 64),   s1 = __shfl(sj, j+1, 64);
                        int   s2 = __shfl(sj, j+2, 64), s3 = __shfl(sj, j+3, 64);
                        if (lane < F) {
                            float h0 = bf2f(Hb[(long)s0 * 64 + lane]);
                            float h1 = bf2f(Hb[(long)s1 * 64 + lane]);
                            float h2 = bf2f(Hb[(long)s2 * 64 + lane]);
                            float h3 = bf2f(Hb[(long)s3 * 64 + lane]);
                            acc += a0 * h0; acc += a1 * h1; acc += a2 * h2; acc += a3 * h3;
                        }
                    }
                    for (; j < cnt; j++) {
                        float a = __shfl(p, j, 64);
                        int   s = __shfl(sj, j, 64);
                        if (lane < F) acc += a * bf2f(Hb[(long)s * 64 + lane]);
                    }
                }
            }
#pragma unroll
            for (int o = 1; o < 64; o <<= 1) dsum += __shfl_xor(dsum, o, 64);
            res = acc / (dsum + 1e-16f);
        }
        if (lane < F) tile[(wid * 16 + k) * (F + 1) + lane] = res + bias[lane];
    }
    __syncthreads();
    for (int idx = t; idx < F * 64; idx += 256) {
        int c = idx / 64, i = idx % 64;
        long n = n0 + i;
        if (n < N_NODES) outT[(long)c * N_NODES + n] = tile[i * (F + 1) + c];
    }
}

// ---------------- final transpose [132][N] -> [N,132] ----------------
__global__ __launch_bounds__(256) void transpose_out(const float* __restrict__ Xt,
                                                     float* __restrict__ out)
{
    __shared__ float tile[64 * 133];
    int t = threadIdx.x;
    long n0 = (long)blockIdx.x * 64;
    int lane = t & 63, cq = t >> 6;
    for (int c = cq; c < 132; c += 4) {
        long n = n0 + lane;
        float v = (n < N_NODES) ? Xt[(long)c * N_NODES + n] : 0.f;
        tile[lane * 133 + c] = v;
    }
    __syncthreads();
    for (int idx = t; idx < 64 * 132; idx += 256) {
        int r = idx / 132, c = idx % 132;
        long n = n0 + r;
        if (n < N_NODES) out[n * 132 + c] = tile[r * 133 + c];
    }
}

// ---------------- CSR build ----------------
__global__ void hist_kernel(const int* __restrict__ dst, int* __restrict__ deg)
{
    for (long e = (long)blockIdx.x * 256 + threadIdx.x; e < N_EDGES; e += (long)gridDim.x * 256)
        atomicAdd(deg + dst[e], 1);
}

__global__ void scan1(const int* __restrict__ deg, int* __restrict__ rtmp, int* __restrict__ parts)
{
    __shared__ int ls[256];
    int t = threadIdx.x;
    long i = (long)blockIdx.x * 256 + t;
    int v = (i < N_NODES) ? deg[i] : 0;
    ls[t] = v; __syncthreads();
    for (int o = 1; o < 256; o <<= 1) {
        int y = (t >= o) ? ls[t - o] : 0;
        __syncthreads();
        ls[t] += y;
        __syncthreads();
    }
    if (i < N_NODES) rtmp[i] = ls[t] - v;
    if (t == 255) parts[blockIdx.x] = ls[255];
}

__global__ void scan2(int* __restrict__ parts, int nb, int* __restrict__ total_out)
{
    __shared__ int ls[512];
    int t = threadIdx.x;
    int v = (t < nb) ? parts[t] : 0;
    ls[t] = v; __syncthreads();
    for (int o = 1; o < 512; o <<= 1) {
        int y = (t >= o) ? ls[t - o] : 0;
        __syncthreads();
        ls[t] += y;
        __syncthreads();
    }
    if (t < nb) parts[t] = ls[t] - v;
    if (t == 0) total_out[0] = ls[511];
}

__global__ void scan3(const int* __restrict__ rtmp, const int* __restrict__ parts,
                      int* __restrict__ rstart, int* __restrict__ cursor)
{
    long i = (long)blockIdx.x * 256 + threadIdx.x;
    if (i < N_NODES) {
        int v = rtmp[i] + parts[i >> 8];
        rstart[i] = v;
        cursor[i] = v;
    }
}

// stores SRC VALUES in dst-sorted CSR order
__global__ void scatter_k(const int* __restrict__ src, const int* __restrict__ dst,
                          int* __restrict__ cursor, int* __restrict__ csr_src)
{
    for (long e = (long)blockIdx.x * 256 + threadIdx.x; e < N_EDGES; e += (long)gridDim.x * 256) {
        int pos = atomicAdd(cursor + dst[e], 1);
        csr_src[pos] = src[e];
    }
}

// ---------------- host helpers ----------------
static void run_dense_block_t(hipStream_t stream, float* Xt, int C0,
                              const float* convW, int WS,
                              const float* gamma, const float* beta,
                              float* gsum, float* gsq, float* psq)
{
    hipMemsetAsync(gsum, 0, 264 * sizeof(float), stream);
    bn_stats_t<<<dim3(C0, 4), 256, 0, stream>>>(Xt, gsum, gsq);
    for (int i = 0; i < 6; i++) {
        int C = C0 + 12 * i;
        dense_conv2<<<NB, 256, 0, stream>>>(Xt, C, C0, i, convW + (size_t)i * 12 * WS, WS,
                                            gamma + (size_t)i * WS, beta + (size_t)i * WS,
                                            gsum, gsq, psq);
    }
}

template<int F>
static void run_gat(hipStream_t stream, const float* XtIn, int K,
                    const float* W, const float* avec, const float* bias,
                    unsigned short* Hb, float* outT,
                    float* sd, float* ss, const int* rstart, const int* csr_src)
{
    gat_gemm<F><<<GG, 256, 0, stream>>>(XtIn, W, avec, K, Hb, sd, ss);
    gat_aggregate2<F><<<GG, 256, 0, stream>>>(rstart, csr_src, sd, ss, Hb, bias, outT);
}

extern "C" void kernel_launch(void* const* d_in, const int* in_sizes, int n_in,
                              void* d_out, int out_size, void* d_ws, size_t ws_size,
                              hipStream_t stream)
{
    const float* x     = (const float*)d_in[0];
    const int*   src   = (const int*)d_in[1];
    const int*   dst   = (const int*)d_in[2];
    const float* w1    = (const float*)d_in[3];
    const float* b1    = (const float*)d_in[4];
    const float* w2    = (const float*)d_in[5];
    const float* b2    = (const float*)d_in[6];
    const float* w3    = (const float*)d_in[7];
    const float* b3    = (const float*)d_in[8];
    const float* conv1 = (const float*)d_in[9];
    const float* bn1g  = (const float*)d_in[10];
    const float* bn1b  = (const float*)d_in[11];
    const float* g1w   = (const float*)d_in[12];
    const float* g1a   = (const float*)d_in[13];
    const float* g1b   = (const float*)d_in[14];
    const float* conv2 = (const float*)d_in[15];
    const float* bn2g  = (const float*)d_in[16];
    const float* bn2b  = (const float*)d_in[17];
    const float* g2w   = (const float*)d_in[18];
    const float* g2a   = (const float*)d_in[19];
    const float* g2b   = (const float*)d_in[20];
    const float* conv3 = (const float*)d_in[21];
    const float* bn3g  = (const float*)d_in[22];
    const float* bn3b  = (const float*)d_in[23];
    float* out = (float*)d_out;

    char* ws = (char*)d_ws;
    size_t off = 0;
    auto alloc = [&](size_t bytes) -> void* {
        void* p = ws + off;
        off += (bytes + 255) & ~(size_t)255;
        return p;
    };
    float*    h      = (float*)alloc((size_t)N_NODES * 256 * 4); // MLP f32; later Hb + Xt3
    float*    Xt1    = (float*)alloc((size_t)96  * N_NODES * 4);
    float*    Xt2    = (float*)alloc((size_t)120 * N_NODES * 4);
    int*      csr_src= (int*)alloc((size_t)N_EDGES * 4);
    int*      deg    = (int*)alloc((size_t)N_NODES * 4);
    int*      rtmp   = (int*)alloc((size_t)N_NODES * 4);
    int*      rstart = (int*)alloc((size_t)(N_NODES + 1) * 4);
    int*      cursor = (int*)alloc((size_t)N_NODES * 4);
    int*      parts  = (int*)alloc(2048);
    float*    sd     = (float*)alloc((size_t)N_NODES * 4);
    float*    ss     = (float*)alloc((size_t)N_NODES * 4);
    float*    gsum   = (float*)alloc(264 * 4);
    float*    gsq    = gsum + 132;
    float*    psq    = (float*)alloc((size_t)2 * 6 * 12 * NB * 4);
    unsigned short* wt1h = (unsigned short*)alloc(256 * 64  * 2);
    unsigned short* wt1l = (unsigned short*)alloc(256 * 64  * 2);
    unsigned short* wt2h = (unsigned short*)alloc(256 * 256 * 2);
    unsigned short* wt2l = (unsigned short*)alloc(256 * 256 * 2);
    unsigned short* wt3h = (unsigned short*)alloc(32  * 256 * 2);
    unsigned short* wt3l = (unsigned short*)alloc(32  * 256 * 2);

    // overlays in h (102.4 MB), dead after the MLP:
    unsigned short* Hb  = (unsigned short*)h;            // [N][64] bf16 = 12.8 MB (128B rows)
    float* Xt3 = (float*)((char*)h + (size_t)16 * 1024 * 1024); // [132][N] f32 = 52.8 MB

    // ---- CSR by dst (shared by both GATs), payload = src values ----
    hipMemsetAsync(deg, 0, (size_t)N_NODES * 4, stream);
    hist_kernel<<<2048, 256, 0, stream>>>(dst, deg);
    scan1<<<NODE_GRID, 256, 0, stream>>>(deg, rtmp, parts);
    scan2<<<1, 512, 0, stream>>>(parts, NODE_GRID, rstart + N_NODES);
    scan3<<<NODE_GRID, 256, 0, stream>>>(rtmp, parts, rstart, cursor);
    scatter_k<<<2048, 256, 0, stream>>>(src, dst, cursor, csr_src);

    // ---- weight prep (f32 -> transposed hi/lo bf16) ----
    cvt_wT_split<<<(256 * 64  + 255) / 256, 256, 0, stream>>>(w1, wt1h, wt1l, 64,  256, 256);
    cvt_wT_split<<<(256 * 256 + 255) / 256, 256, 0, stream>>>(w2, wt2h, wt2l, 256, 256, 256);
    cvt_wT_split<<<(32  * 256 + 255) / 256, 256, 0, stream>>>(w3, wt3h, wt3l, 256, 24,  32);

    // ---- MLP (hi/lo bf16 MFMA, ~f32 precision, f32 intermediates) ----
    mlp_mfma_hilo<64> <<<GG, 256, 0, stream>>>(x, wt1h, wt1l, b1, h);
    mlp_mfma_hilo<256><<<GG, 256, 0, stream>>>(h, wt2h, wt2l, b2, h);   // in-place
    mlp_mfma24_hilo<<<GG, 256, 0, stream>>>(h, wt3h, wt3l, b3, Xt1);

    // ---- dense block 1 (24 -> 96, channel-major) ----
    run_dense_block_t(stream, Xt1, 24, conv1, 84, bn1g, bn1b, gsum, gsq, psq);

    // ---- GAT 1 (96 -> 48), output transposed into Xt2 rows 0..47 ----
    run_gat<48>(stream, Xt1, 96, g1w, g1a, g1b, Hb, Xt2, sd, ss, rstart, csr_src);

    // ---- dense block 2 (48 -> 120) ----
    run_dense_block_t(stream, Xt2, 48, conv2, 108, bn2g, bn2b, gsum, gsq, psq);

    // ---- GAT 2 (120 -> 60), output transposed into Xt3 rows 0..59 ----
    run_gat<60>(stream, Xt2, 120, g2w, g2a, g2b, Hb, Xt3, sd, ss, rstart, csr_src);

    // ---- dense block 3 (60 -> 132) ----
    run_dense_block_t(stream, Xt3, 60, conv3, 120, bn3g, bn3b, gsum, gsq, psq);

    // ---- final transpose to row-major d_out ----
    transpose_out<<<GG, 256, 0, stream>>>(Xt3, out);
}